// Round 1
// baseline (549.467 us; speedup 1.0000x reference)
//
#include <hip/hip_runtime.h>

// MaxPool2d 2x2 stride 2 on (32, 64, 224, 224) fp32 -> (32, 64, 112, 112).
// 224 even => SAME padding is zero; every output = max of a disjoint 2x2 block.
// Memory-bound: 411 MB read + 103 MB write => ~82 us floor at 6.3 TB/s.
//
// Each grid-stride iteration produces one float4 of output (4 consecutive
// output columns) from 2x float4 loads per input row x 2 rows (64 B in,
// 16 B out). All float4 accesses are 16B-aligned (offsets 0/4/224/228 floats
// are all multiples of 4; row stride 224 is a multiple of 4).

#define TOTAL_QUADS (32 * 64 * 112 * 28)  // 6,422,528 output float4s

__global__ __launch_bounds__(256) void maxpool_2x2_kernel(
    const float* __restrict__ in, float* __restrict__ out) {
    const int total = TOTAL_QUADS;
    const int stride = gridDim.x * blockDim.x;
    for (int q = blockIdx.x * blockDim.x + threadIdx.x; q < total; q += stride) {
        // q -> (plane p = n*64+c, output row oh, quad-in-row qi)
        const int r  = q / 28;        // output row index across all planes
        const int qi = q - r * 28;    // which float4 within the 112-wide row
        const int p  = r / 112;       // plane index (n*C + c)
        const int oh = r - p * 112;   // output row within plane

        const float* src = in + (size_t)p * (224 * 224)
                              + (size_t)(2 * oh) * 224
                              + (size_t)qi * 8;

        const float4 a0 = *reinterpret_cast<const float4*>(src);        // row0 [0..3]
        const float4 a1 = *reinterpret_cast<const float4*>(src + 4);    // row0 [4..7]
        const float4 b0 = *reinterpret_cast<const float4*>(src + 224);  // row1 [0..3]
        const float4 b1 = *reinterpret_cast<const float4*>(src + 228);  // row1 [4..7]

        float4 o;
        o.x = fmaxf(fmaxf(a0.x, a0.y), fmaxf(b0.x, b0.y));
        o.y = fmaxf(fmaxf(a0.z, a0.w), fmaxf(b0.z, b0.w));
        o.z = fmaxf(fmaxf(a1.x, a1.y), fmaxf(b1.x, b1.y));
        o.w = fmaxf(fmaxf(a1.z, a1.w), fmaxf(b1.z, b1.w));

        *reinterpret_cast<float4*>(out + (size_t)q * 4) = o;
    }
}

extern "C" void kernel_launch(void* const* d_in, const int* in_sizes, int n_in,
                              void* d_out, int out_size, void* d_ws, size_t ws_size,
                              hipStream_t stream) {
    const float* X = (const float*)d_in[0];
    float* out = (float*)d_out;
    // 2048 blocks x 256 threads = 32 waves/CU across 256 CUs (max occupancy);
    // each thread grid-strides ~12 quads, amortizing the index math.
    maxpool_2x2_kernel<<<2048, 256, 0, stream>>>(X, out);
}